// Round 7
// baseline (185.891 us; speedup 1.0000x reference)
//
#include <hip/hip_runtime.h>
#include <math.h>

// Problem constants (fixed shapes from reference)
#define B_ 2
#define N_ 16384
#define M_ 12000
#define F_ 16384

#define P_ 128          // face partitions (argmin granularity)
#define TILE_ 128       // faces per partition
#define NCHUNK_ 8       // face chunks (knn blocks per vert-block)

typedef short bf16x8 __attribute__((ext_vector_type(8)));
typedef float f32x16 __attribute__((ext_vector_type(16)));

__device__ __host__ inline unsigned short bf16rn(float x) {
  unsigned int u = __float_as_uint(x);
  u = (u + 0x7FFFu + ((u >> 16) & 1u)) >> 16;
  return (unsigned short)u;
}
__device__ inline float bf16tof(unsigned short h) {
  return __uint_as_float(((unsigned int)h) << 16);
}

// async global->LDS, 16B per lane. LDS dest must be wave-uniform base;
// HW writes base + lane*16 (linear). Global src is per-lane.
__device__ __forceinline__ void gload_lds16(const uint4* g, uint4* l) {
  __builtin_amdgcn_global_load_lds(
      (const __attribute__((address_space(1))) void*)g,
      (__attribute__((address_space(3))) void*)l, 16, 0, 0);
}

// ---------------------------------------------------------------------------
// Kernel A: per-face precompute + out[0] zero-init + cnt[] zero (R15
// wave-split form: wave 0 = obs_curr chain -> fcurr/fpack, wave 1 =
// obs_next chain -> fnext; wave-uniform branch, no load amplification).
// ---------------------------------------------------------------------------
__global__ __launch_bounds__(128) void face_precomp(
    const float* __restrict__ obs_curr,
    const float* __restrict__ obs_next,
    const int* __restrict__ faces,
    float4* __restrict__ fcurr,
    float4* __restrict__ fnext,
    uint4* __restrict__ fpack,
    float* __restrict__ out,
    int* __restrict__ cnt) {
  int lane = threadIdx.x & 63;
  int half = threadIdx.x >> 6;        // 0: fcurr/fpack, 1: fnext
  int t = blockIdx.x * 64 + lane;     // face slot in [0, B*F)
  if (blockIdx.x == 0 && threadIdx.x == 0) out[0] = 0.0f;
  if (blockIdx.x == 0 && half == 1) cnt[lane] = 0;  // 64 vb-counters
  int b = t / F_;
  const int* fidx3 = faces + 3 * (size_t)t;
  int i0 = fidx3[0];
  int i1 = fidx3[1];
  int i2 = fidx3[2];

  if (half == 0) {
    const float* oc = obs_curr + (size_t)b * M_ * 3;
    float ax = oc[3*i0], ay = oc[3*i0+1], az = oc[3*i0+2];
    float bx = oc[3*i1], by = oc[3*i1+1], bz = oc[3*i1+2];
    float cx = oc[3*i2], cy = oc[3*i2+1], cz = oc[3*i2+2];
    float gx = (ax + bx + cx) / 3.0f;
    float gy = (ay + by + cy) / 3.0f;
    float gz = (az + bz + cz) / 3.0f;
    float w = gx*gx + gy*gy + gz*gz;
    fcurr[t] = make_float4(gx, gy, gz, w);

    float fx = -2.0f * gx, fy = -2.0f * gy, fz = -2.0f * gz;
    unsigned short fhx = bf16rn(fx), flx = bf16rn(fx - bf16tof(fhx));
    unsigned short fhy = bf16rn(fy), fly = bf16rn(fy - bf16tof(fhy));
    unsigned short fhz = bf16rn(fz), flz = bf16rn(fz - bf16tof(fhz));
    unsigned short whi = bf16rn(w),  wlo = bf16rn(w - bf16tof(whi));
    uint4 r0, r1;
    r0.x = (unsigned)fhx | ((unsigned)flx << 16);  // k0,k1
    r0.y = r0.x;                                    // k2,k3
    r0.z = (unsigned)fhy | ((unsigned)fly << 16);  // k4,k5
    r0.w = r0.z;                                    // k6,k7
    r1.x = (unsigned)fhz | ((unsigned)flz << 16);  // k8,k9
    r1.y = r1.x;                                    // k10,k11
    r1.z = (unsigned)whi | ((unsigned)wlo << 16);  // k12,k13
    r1.w = 0;                                       // k14,k15
    fpack[(size_t)t * 2 + 0] = r0;
    fpack[(size_t)t * 2 + 1] = r1;
  } else {
    const float* on = obs_next + (size_t)b * M_ * 3;
    float nax = on[3*i0], nay = on[3*i0+1], naz = on[3*i0+2];
    float nbx = on[3*i1], nby = on[3*i1+1], nbz = on[3*i1+2];
    float ncx = on[3*i2], ncy = on[3*i2+1], ncz = on[3*i2+2];
    float hx = (nax + nbx + ncx) / 3.0f;
    float hy = (nay + nby + ncy) / 3.0f;
    float hz = (naz + nbz + ncz) / 3.0f;
    float e1x = nbx - nax, e1y = nby - nay, e1z = nbz - naz;
    float e2x = ncx - nax, e2y = ncy - nay, e2z = ncz - naz;
    float crx = e1y * e2z - e1z * e2y;
    float cry = e1z * e2x - e1x * e2z;
    float crz = e1x * e2y - e1y * e2x;
    float len = sqrtf(crx*crx + cry*cry + crz*crz);
    float inv = 1.0f / (len + 1e-12f);
    fnext[2 * (size_t)t + 0] = make_float4(hx, hy, hz, 0.0f);
    fnext[2 * (size_t)t + 1] = make_float4(crx*inv, cry*inv, crz*inv, 0.0f);
  }
}

// ---------------------------------------------------------------------------
// Kernel B (fused): 32x32x16 MFMA approximate-min pass + last-arriver
// epilogue. Hot loop is VERBATIM the R15/R2-verified form (frozen).
// Tail: after the pchunk store, each block does threadfence + atomicAdd
// on cnt[vb]; the 16th arriver (8 chunks x 2 batches) runs the epilogue
// inline for its 256 verts, BOTH batches per thread (fused loops -> 2x
// independent load streams). Deadlock-free (no spin), dispatch-order
// independent, device-scope fences for cross-XCD visibility (G16).
// ---------------------------------------------------------------------------
__global__ __launch_bounds__(256, 4) void knn_mfma32(
    const float* __restrict__ cloth_curr,
    const uint4* __restrict__ fpack,     // 2 x uint4 per face (32 B)
    float2* __restrict__ pchunk,         // [B][NCHUNK][N] (minval, part-idx)
    const float* __restrict__ cloth_next,
    const float4* __restrict__ fcurr,
    const float4* __restrict__ fnext,
    const int* __restrict__ iter_num,
    float* __restrict__ out,
    int* __restrict__ cnt) {
  __shared__ uint4 abuf[2][256];   // 2 x 4 KB: one 128-face partition each

  int bid = blockIdx.x;            // [0, 1024)
  int s   = bid & 7;               // face chunk: [s*2048, (s+1)*2048)
  int vb  = (bid >> 3) & 63;       // 256-vert block
  int b   = bid >> 9;              // batch
  int lane = threadIdx.x & 63;
  int wid  = threadIdx.x >> 6;     // 0..3
  int h = lane >> 5;               // k-half
  int m = lane & 31;               // face-row / vert-col
  int vw = vb * 256 + wid * 64;    // wave's 64 verts

  // 2 B-frags: frag g covers verts vw + g*32 + m (col=lane&31, k=8*h+j)
  const short one = (short)0x3F80;
  bf16x8 bfrag0, bfrag1;
#pragma unroll
  for (int g = 0; g < 2; ++g) {
    const float* cp = cloth_curr + ((size_t)b * N_ + vw + g * 32 + m) * 3;
    float cxx = cp[0], cyy = cp[1], czz = cp[2];
    unsigned short chx = bf16rn(cxx), clx = bf16rn(cxx - bf16tof(chx));
    unsigned short chy = bf16rn(cyy), cly = bf16rn(cyy - bf16tof(chy));
    unsigned short chz = bf16rn(czz), clz = bf16rn(czz - bf16tof(chz));
    bf16x8 tq;
    if (h == 0) {
      tq[0] = (short)chx; tq[1] = (short)chx;
      tq[2] = (short)clx; tq[3] = (short)clx;
      tq[4] = (short)chy; tq[5] = (short)chy;
      tq[6] = (short)cly; tq[7] = (short)cly;
    } else {
      tq[0] = (short)chz; tq[1] = (short)chz;
      tq[2] = (short)clz; tq[3] = (short)clz;
      tq[4] = one; tq[5] = one;
      tq[6] = 0;   tq[7] = 0;
    }
    if (g == 0) bfrag0 = tq; else bfrag1 = tq;
  }

  f32x16 zc;
#pragma unroll
  for (int k = 0; k < 16; ++k) zc[k] = 0.0f;

  // chunk base (uint4 units): 2048 faces * 2 uint4. Partition = 256 uint4.
  const uint4* chunk = fpack + ((size_t)b * F_ + (size_t)s * 2048) * 2;

  // prologue: stage partition 0 into abuf[0] (each thread one 16B lane-slot)
  gload_lds16(chunk + wid * 64 + lane, &abuf[0][wid * 64]);
  __syncthreads();   // compiler drains vmcnt(0) before s_barrier

  // running chunk-level (min, argmin partition) per covered vert
  float rb0 = 3.4e38f, rb1 = 3.4e38f;
  int   rp0 = 0,       rp1 = 0;

  for (int part = 0; part < 16; ++part) {
    int cur = part & 1;
    // issue next partition's staging into the other buffer (no wait)
    if (part < 15)
      gload_lds16(chunk + (part + 1) * 256 + wid * 64 + lane,
                  &abuf[cur ^ 1][wid * 64]);

    float r0[8], r1[8];
#pragma unroll
    for (int k = 0; k < 8; ++k) { r0[k] = 3.4e38f; r1[k] = 3.4e38f; }

    // A-frag (face m of tile, half h) from LDS: idx (grp*64+m)*2+h and +32
    const uint4* lp = &abuf[cur][m * 2 + h];
#pragma unroll
    for (int grp = 0; grp < 2; ++grp) {   // 2 groups of 2 tiles
      uint4 a0 = lp[grp * 128];
      uint4 a1 = lp[grp * 128 + 64];
      bf16x8 av0 = __builtin_bit_cast(bf16x8, a0);
      bf16x8 av1 = __builtin_bit_cast(bf16x8, a1);
      f32x16 d00 = __builtin_amdgcn_mfma_f32_32x32x16_bf16(av0, bfrag0, zc, 0, 0, 0);
      f32x16 d01 = __builtin_amdgcn_mfma_f32_32x32x16_bf16(av0, bfrag1, zc, 0, 0, 0);
      f32x16 d10 = __builtin_amdgcn_mfma_f32_32x32x16_bf16(av1, bfrag0, zc, 0, 0, 0);
      f32x16 d11 = __builtin_amdgcn_mfma_f32_32x32x16_bf16(av1, bfrag1, zc, 0, 0, 0);
      // per-k running accumulators; min(min(a,b),c) fuses to v_min3_f32
#pragma unroll
      for (int k = 0; k < 8; ++k) {
        r0[k] = fminf(fminf(d00[k], d00[k + 8]), r0[k]);
        r0[k] = fminf(fminf(d10[k], d10[k + 8]), r0[k]);
        r1[k] = fminf(fminf(d01[k], d01[k + 8]), r1[k]);
        r1[k] = fminf(fminf(d11[k], d11[k + 8]), r1[k]);
      }
    }
    // fold 8 -> 1 per frag, merge halves
    float t0 = fminf(fminf(r0[0], r0[1]), r0[2]);
    t0 = fminf(fminf(t0, r0[3]), r0[4]);
    t0 = fminf(fminf(t0, r0[5]), r0[6]);
    float bmin0 = fminf(t0, r0[7]);
    float t1 = fminf(fminf(r1[0], r1[1]), r1[2]);
    t1 = fminf(fminf(t1, r1[3]), r1[4]);
    t1 = fminf(fminf(t1, r1[5]), r1[6]);
    float bmin1 = fminf(t1, r1[7]);
    bmin0 = fminf(bmin0, __shfl_xor(bmin0, 32, 64));
    bmin1 = fminf(bmin1, __shfl_xor(bmin1, 32, 64));

    // running argmin (strict <, ascending part => first-min-wins)
    bool u0 = bmin0 < rb0;
    rb0 = u0 ? bmin0 : rb0;
    rp0 = u0 ? part : rp0;
    bool u1 = bmin1 < rb1;
    rb1 = u1 ? bmin1 : rb1;
    rp1 = u1 ? part : rp1;

    // drain staging (vmcnt) + cross-wave LDS visibility for next partition
    if (part < 15) __syncthreads();
  }

  // one store per vert: (chunk-min, global partition index)
  float2* pout = pchunk + ((size_t)(b * NCHUNK_ + s)) * N_ + vw;
  if (lane < 32) {
    pout[lane]      = make_float2(rb0, __int_as_float(s * 16 + rp0));
    pout[32 + lane] = make_float2(rb1, __int_as_float(s * 16 + rp1));
  }

  // ---- last-arriver epilogue for this vb (16 arrivals: 8 chunks x 2 b) ----
  __syncthreads();                    // all pchunk stores of this block done
  __shared__ int lastflag;
  if (threadIdx.x == 0) {
    __threadfence();                  // release: flush this XCD's L2
    int old = atomicAdd(&cnt[vb], 1);
    lastflag = (old == 15);
  }
  __syncthreads();
  if (!lastflag) return;
  __threadfence();                    // acquire: invalidate for cross-XCD reads

  int tid = threadIdx.x;
  int i = vb * 256 + tid;             // this thread's vertex (both batches)

  // weight ramp (double to match Python scalar math)
  int itv = *iter_num;
  double itc = (double)(itv - 50000);
  if (itc < 0.0) itc = 0.0;
  double prog = itc / 100000.0;
  if (prog > 1.0) prog = 1.0;
  float weight = (float)(1e-3 + (5e3 - 1e-3) * prog);
  float scale = weight * 0.5f;  // weight / B

  // pass 1 (both batches fused): argmin partition over chunk minima
  float best0 = 3.4e38f, best1 = 3.4e38f;
  int bp0 = 0, bp1 = 0;
#pragma unroll
  for (int c = 0; c < NCHUNK_; ++c) {
    float2 v0 = pchunk[((size_t)c) * N_ + i];
    float2 v1 = pchunk[((size_t)(NCHUNK_ + c)) * N_ + i];
    bool m0 = v0.x < best0;
    best0 = m0 ? v0.x : best0;
    bp0 = m0 ? __float_as_int(v0.y) : bp0;
    bool m1 = v1.x < best1;
    best1 = m1 ? v1.x : best1;
    bp1 = m1 ? __float_as_int(v1.y) : bp1;
  }

  // independent per-vert loads
  const float* cp0 = cloth_curr + (size_t)i * 3;
  const float* cp1 = cloth_curr + ((size_t)N_ + i) * 3;
  float ax0 = -2.0f * cp0[0], ay0 = -2.0f * cp0[1], az0 = -2.0f * cp0[2];
  float ax1 = -2.0f * cp1[0], ay1 = -2.0f * cp1[1], az1 = -2.0f * cp1[2];
  const float* nq0 = cloth_next + (size_t)i * 3;
  const float* nq1 = cloth_next + ((size_t)N_ + i) * 3;
  float nx0 = nq0[0], ny0 = nq0[1], nz0 = nq0[2];
  float nx1 = nq1[0], ny1 = nq1[1], nz1 = nq1[2];

  // pass 2 (both batches fused): exact fp32 rescan of winning partitions
  const float4* fA = fcurr + (size_t)bp0 * TILE_;
  const float4* fB = fcurr + (size_t)F_ + (size_t)bp1 * TILE_;
  float s0 = 3.4e38f, s1 = 3.4e38f;
  int j0 = 0, j1 = 0;
#pragma unroll 4
  for (int j = 0; j < TILE_; ++j) {
    float4 fa = fA[j];
    float fb_s;
    float4 fb = fB[j];
    float sa = fmaf(ax0, fa.x, fmaf(ay0, fa.y, fmaf(az0, fa.z, fa.w)));
    fb_s = fmaf(ax1, fb.x, fmaf(ay1, fb.y, fmaf(az1, fb.z, fb.w)));
    bool u0 = sa < s0;
    s0 = u0 ? sa : s0;
    j0 = u0 ? j : j0;
    bool u1 = fb_s < s1;
    s1 = u1 ? fb_s : s1;
    j1 = u1 ? j : j1;
  }
  int f0 = bp0 * TILE_ + j0;
  int f1 = F_ + bp1 * TILE_ + j1;

  float4 c0 = fnext[2 * (size_t)f0 + 0];
  float4 nr0 = fnext[2 * (size_t)f0 + 1];
  float4 c1 = fnext[2 * (size_t)f1 + 0];
  float4 nr1 = fnext[2 * (size_t)f1 + 1];
  float d0 = (nx0 - c0.x) * nr0.x + (ny0 - c0.y) * nr0.y + (nz0 - c0.z) * nr0.z;
  float d1 = (nx1 - c1.x) * nr1.x + (ny1 - c1.y) * nr1.y + (nz1 - c1.z) * nr1.z;
  float ip0 = fmaxf(1e-3f - d0, 0.0f);
  float ip1 = fmaxf(1e-3f - d1, 0.0f);
  float acc0 = ip0 * ip0 * ip0 * scale;   // keep per-batch scale mul order
  float acc1 = ip1 * ip1 * ip1 * scale;   // (matches prior rounding)
  float pair = acc0 + acc1;

  out[1 + i] = pair;  // per_vert

  // block-level loss partial -> one atomic per block (4 waves)
  float r = pair;
#pragma unroll
  for (int off = 32; off > 0; off >>= 1) r += __shfl_down(r, off, 64);
  __shared__ float wsum[4];
  if (lane == 0) wsum[wid] = r;
  __syncthreads();
  if (threadIdx.x == 0)
    atomicAdd(out, (wsum[0] + wsum[1]) + (wsum[2] + wsum[3]));
}

// ---------------------------------------------------------------------------
extern "C" void kernel_launch(void* const* d_in, const int* in_sizes, int n_in,
                              void* d_out, int out_size, void* d_ws, size_t ws_size,
                              hipStream_t stream) {
  const float* cloth_curr = (const float*)d_in[0];
  const float* cloth_next = (const float*)d_in[1];
  const float* obs_curr   = (const float*)d_in[2];
  const float* obs_next   = (const float*)d_in[3];
  const int*   faces      = (const int*)d_in[4];
  const int*   iter_num   = (const int*)d_in[5];
  float* out = (float*)d_out;

  // workspace: fcurr 512K @0 | fnext 1M @512K | fpack 1M @1.5M |
  //            pchunk 2M @3.5M | cnt 256B @5.5M
  char* w = (char*)d_ws;
  float4* fcurr = (float4*)(w);
  float4* fnext = (float4*)(w + 524288);
  uint4*  fpack = (uint4*)(w + 1572864);
  float2* pchunk = (float2*)(w + 3670016);
  int*    cnt   = (int*)(w + 5767168);

  // wave-split: 512 blocks x 128 threads, block = 2 waves over 64 faces
  face_precomp<<<(B_ * F_) / 64, 128, 0, stream>>>(
      obs_curr, obs_next, faces, fcurr, fnext, fpack, out, cnt);

  knn_mfma32<<<1024, 256, 0, stream>>>(
      cloth_curr, fpack, pchunk, cloth_next, fcurr, fnext, iter_num, out, cnt);
}

// Round 8
// 104.369 us; speedup vs baseline: 1.7811x; 1.7811x over previous
//
#include <hip/hip_runtime.h>
#include <math.h>

// Problem constants (fixed shapes from reference)
#define B_ 2
#define N_ 16384
#define M_ 12000
#define F_ 16384

#define P_ 128          // face partitions (argmin granularity)
#define TILE_ 128       // faces per partition
#define NCHUNK_ 8       // face chunks (knn blocks per vert-block)

typedef short bf16x8 __attribute__((ext_vector_type(8)));
typedef float f32x16 __attribute__((ext_vector_type(16)));

__device__ __host__ inline unsigned short bf16rn(float x) {
  unsigned int u = __float_as_uint(x);
  u = (u + 0x7FFFu + ((u >> 16) & 1u)) >> 16;
  return (unsigned short)u;
}
__device__ inline float bf16tof(unsigned short h) {
  return __uint_as_float(((unsigned int)h) << 16);
}

// async global->LDS, 16B per lane. LDS dest must be wave-uniform base;
// HW writes base + lane*16 (linear). Global src is per-lane.
__device__ __forceinline__ void gload_lds16(const uint4* g, uint4* l) {
  __builtin_amdgcn_global_load_lds(
      (const __attribute__((address_space(1))) void*)g,
      (__attribute__((address_space(3))) void*)l, 16, 0, 0);
}

// ---------------------------------------------------------------------------
// Kernel A: per-face precompute + out[0] zero-init.
// R15 wave-split form (verified 104.55): block = 2 waves over 64 faces;
// wave 0 does the obs_curr chain (fcurr + fpack), wave 1 the obs_next
// chain (fnext). Wave-uniform branch, no load amplification. R7 lesson:
// do NOT fuse the pipeline into one kernel — per-block device-scope
// fences (L2 wb/inv on non-coherent XCD L2s) cost ~0.13 us each and
// serialized to 137 us at grid 1024. Stream-ordered kernel boundaries
// are the cheap device-wide release.
// ---------------------------------------------------------------------------
__global__ __launch_bounds__(128) void face_precomp(
    const float* __restrict__ obs_curr,
    const float* __restrict__ obs_next,
    const int* __restrict__ faces,
    float4* __restrict__ fcurr,
    float4* __restrict__ fnext,
    uint4* __restrict__ fpack,
    float* __restrict__ out) {
  int lane = threadIdx.x & 63;
  int half = threadIdx.x >> 6;        // 0: fcurr/fpack, 1: fnext
  int t = blockIdx.x * 64 + lane;     // face slot in [0, B*F)
  if (blockIdx.x == 0 && threadIdx.x == 0) out[0] = 0.0f;
  int b = t / F_;
  const int* fidx3 = faces + 3 * (size_t)t;
  int i0 = fidx3[0];
  int i1 = fidx3[1];
  int i2 = fidx3[2];

  if (half == 0) {
    const float* oc = obs_curr + (size_t)b * M_ * 3;
    float ax = oc[3*i0], ay = oc[3*i0+1], az = oc[3*i0+2];
    float bx = oc[3*i1], by = oc[3*i1+1], bz = oc[3*i1+2];
    float cx = oc[3*i2], cy = oc[3*i2+1], cz = oc[3*i2+2];
    float gx = (ax + bx + cx) / 3.0f;
    float gy = (ay + by + cy) / 3.0f;
    float gz = (az + bz + cz) / 3.0f;
    float w = gx*gx + gy*gy + gz*gz;
    fcurr[t] = make_float4(gx, gy, gz, w);

    float fx = -2.0f * gx, fy = -2.0f * gy, fz = -2.0f * gz;
    unsigned short fhx = bf16rn(fx), flx = bf16rn(fx - bf16tof(fhx));
    unsigned short fhy = bf16rn(fy), fly = bf16rn(fy - bf16tof(fhy));
    unsigned short fhz = bf16rn(fz), flz = bf16rn(fz - bf16tof(fhz));
    unsigned short whi = bf16rn(w),  wlo = bf16rn(w - bf16tof(whi));
    uint4 r0, r1;
    r0.x = (unsigned)fhx | ((unsigned)flx << 16);  // k0,k1
    r0.y = r0.x;                                    // k2,k3
    r0.z = (unsigned)fhy | ((unsigned)fly << 16);  // k4,k5
    r0.w = r0.z;                                    // k6,k7
    r1.x = (unsigned)fhz | ((unsigned)flz << 16);  // k8,k9
    r1.y = r1.x;                                    // k10,k11
    r1.z = (unsigned)whi | ((unsigned)wlo << 16);  // k12,k13
    r1.w = 0;                                       // k14,k15
    fpack[(size_t)t * 2 + 0] = r0;
    fpack[(size_t)t * 2 + 1] = r1;
  } else {
    const float* on = obs_next + (size_t)b * M_ * 3;
    float nax = on[3*i0], nay = on[3*i0+1], naz = on[3*i0+2];
    float nbx = on[3*i1], nby = on[3*i1+1], nbz = on[3*i1+2];
    float ncx = on[3*i2], ncy = on[3*i2+1], ncz = on[3*i2+2];
    float hx = (nax + nbx + ncx) / 3.0f;
    float hy = (nay + nby + ncy) / 3.0f;
    float hz = (naz + nbz + ncz) / 3.0f;
    float e1x = nbx - nax, e1y = nby - nay, e1z = nbz - naz;
    float e2x = ncx - nax, e2y = ncy - nay, e2z = ncz - naz;
    float crx = e1y * e2z - e1z * e2y;
    float cry = e1z * e2x - e1x * e2z;
    float crz = e1x * e2y - e1y * e2x;
    float len = sqrtf(crx*crx + cry*cry + crz*crz);
    float inv = 1.0f / (len + 1e-12f);
    fnext[2 * (size_t)t + 0] = make_float4(hx, hy, hz, 0.0f);
    fnext[2 * (size_t)t + 1] = make_float4(crx*inv, cry*inv, crz*inv, 0.0f);
  }
}

// ---------------------------------------------------------------------------
// Kernel B: 32x32x16 MFMA approximate-min pass (R2-verified form — best of
// R10/R13 variants; pair-staging regressed in R4, fusion regressed in R7;
// leave this kernel alone). VALU-bound ~4.5 us vs ~3.4 us min3 floor; MFMA
// 1.7 us hides under it. Chunk-level (min, argmin-partition) in registers;
// ONE float2 store per vert per chunk. LDS 4 KB partition double-buffered
// via global_load_lds.
// ---------------------------------------------------------------------------
__global__ __launch_bounds__(256, 4) void knn_mfma32(
    const float* __restrict__ cloth_curr,
    const uint4* __restrict__ fpack,     // 2 x uint4 per face (32 B)
    float2* __restrict__ pchunk) {       // [B][NCHUNK][N] (minval, part-idx)
  __shared__ uint4 abuf[2][256];   // 2 x 4 KB: one 128-face partition each

  int bid = blockIdx.x;            // [0, 1024)
  int s   = bid & 7;               // face chunk: [s*2048, (s+1)*2048)
  int vb  = (bid >> 3) & 63;       // 256-vert block
  int b   = bid >> 9;              // batch
  int lane = threadIdx.x & 63;
  int wid  = threadIdx.x >> 6;     // 0..3
  int h = lane >> 5;               // k-half
  int m = lane & 31;               // face-row / vert-col
  int vw = vb * 256 + wid * 64;    // wave's 64 verts

  // 2 B-frags: frag g covers verts vw + g*32 + m (col=lane&31, k=8*h+j)
  const short one = (short)0x3F80;
  bf16x8 bfrag0, bfrag1;
#pragma unroll
  for (int g = 0; g < 2; ++g) {
    const float* cp = cloth_curr + ((size_t)b * N_ + vw + g * 32 + m) * 3;
    float cxx = cp[0], cyy = cp[1], czz = cp[2];
    unsigned short chx = bf16rn(cxx), clx = bf16rn(cxx - bf16tof(chx));
    unsigned short chy = bf16rn(cyy), cly = bf16rn(cyy - bf16tof(chy));
    unsigned short chz = bf16rn(czz), clz = bf16rn(czz - bf16tof(chz));
    bf16x8 tq;
    if (h == 0) {
      tq[0] = (short)chx; tq[1] = (short)chx;
      tq[2] = (short)clx; tq[3] = (short)clx;
      tq[4] = (short)chy; tq[5] = (short)chy;
      tq[6] = (short)cly; tq[7] = (short)cly;
    } else {
      tq[0] = (short)chz; tq[1] = (short)chz;
      tq[2] = (short)clz; tq[3] = (short)clz;
      tq[4] = one; tq[5] = one;
      tq[6] = 0;   tq[7] = 0;
    }
    if (g == 0) bfrag0 = tq; else bfrag1 = tq;
  }

  f32x16 zc;
#pragma unroll
  for (int k = 0; k < 16; ++k) zc[k] = 0.0f;

  // chunk base (uint4 units): 2048 faces * 2 uint4. Partition = 256 uint4.
  const uint4* chunk = fpack + ((size_t)b * F_ + (size_t)s * 2048) * 2;

  // prologue: stage partition 0 into abuf[0] (each thread one 16B lane-slot)
  gload_lds16(chunk + wid * 64 + lane, &abuf[0][wid * 64]);
  __syncthreads();   // compiler drains vmcnt(0) before s_barrier

  // running chunk-level (min, argmin partition) per covered vert
  float rb0 = 3.4e38f, rb1 = 3.4e38f;
  int   rp0 = 0,       rp1 = 0;

  for (int part = 0; part < 16; ++part) {
    int cur = part & 1;
    // issue next partition's staging into the other buffer (no wait)
    if (part < 15)
      gload_lds16(chunk + (part + 1) * 256 + wid * 64 + lane,
                  &abuf[cur ^ 1][wid * 64]);

    float r0[8], r1[8];
#pragma unroll
    for (int k = 0; k < 8; ++k) { r0[k] = 3.4e38f; r1[k] = 3.4e38f; }

    // A-frag (face m of tile, half h) from LDS: idx (grp*64+m)*2+h and +32
    const uint4* lp = &abuf[cur][m * 2 + h];
#pragma unroll
    for (int grp = 0; grp < 2; ++grp) {   // 2 groups of 2 tiles
      uint4 a0 = lp[grp * 128];
      uint4 a1 = lp[grp * 128 + 64];
      bf16x8 av0 = __builtin_bit_cast(bf16x8, a0);
      bf16x8 av1 = __builtin_bit_cast(bf16x8, a1);
      f32x16 d00 = __builtin_amdgcn_mfma_f32_32x32x16_bf16(av0, bfrag0, zc, 0, 0, 0);
      f32x16 d01 = __builtin_amdgcn_mfma_f32_32x32x16_bf16(av0, bfrag1, zc, 0, 0, 0);
      f32x16 d10 = __builtin_amdgcn_mfma_f32_32x32x16_bf16(av1, bfrag0, zc, 0, 0, 0);
      f32x16 d11 = __builtin_amdgcn_mfma_f32_32x32x16_bf16(av1, bfrag1, zc, 0, 0, 0);
      // per-k running accumulators; min(min(a,b),c) fuses to v_min3_f32
#pragma unroll
      for (int k = 0; k < 8; ++k) {
        r0[k] = fminf(fminf(d00[k], d00[k + 8]), r0[k]);
        r0[k] = fminf(fminf(d10[k], d10[k + 8]), r0[k]);
        r1[k] = fminf(fminf(d01[k], d01[k + 8]), r1[k]);
        r1[k] = fminf(fminf(d11[k], d11[k + 8]), r1[k]);
      }
    }
    // fold 8 -> 1 per frag, merge halves
    float t0 = fminf(fminf(r0[0], r0[1]), r0[2]);
    t0 = fminf(fminf(t0, r0[3]), r0[4]);
    t0 = fminf(fminf(t0, r0[5]), r0[6]);
    float bmin0 = fminf(t0, r0[7]);
    float t1 = fminf(fminf(r1[0], r1[1]), r1[2]);
    t1 = fminf(fminf(t1, r1[3]), r1[4]);
    t1 = fminf(fminf(t1, r1[5]), r1[6]);
    float bmin1 = fminf(t1, r1[7]);
    bmin0 = fminf(bmin0, __shfl_xor(bmin0, 32, 64));
    bmin1 = fminf(bmin1, __shfl_xor(bmin1, 32, 64));

    // running argmin (strict <, ascending part => first-min-wins)
    bool u0 = bmin0 < rb0;
    rb0 = u0 ? bmin0 : rb0;
    rp0 = u0 ? part : rp0;
    bool u1 = bmin1 < rb1;
    rb1 = u1 ? bmin1 : rb1;
    rp1 = u1 ? part : rp1;

    // drain staging (vmcnt) + cross-wave LDS visibility for next partition
    if (part < 15) __syncthreads();
  }

  // one store per vert: (chunk-min, global partition index)
  float2* pout = pchunk + ((size_t)(b * NCHUNK_ + s)) * N_ + vw;
  if (lane < 32) {
    pout[lane]      = make_float2(rb0, __int_as_float(s * 16 + rp0));
    pout[32 + lane] = make_float2(rb1, __int_as_float(s * 16 + rp1));
  }
}

// ---------------------------------------------------------------------------
// Kernel C: per-(vertex,batch)-thread epilogue (R2-verified logic, R5 grid,
// R6 unroll-8 + hoisted loads — verified 104.55).
// ---------------------------------------------------------------------------
__global__ __launch_bounds__(128) void epilogue(
    const float* __restrict__ cloth_curr,
    const float* __restrict__ cloth_next,
    const float4* __restrict__ fcurr,
    const float4* __restrict__ fnext,
    const float2* __restrict__ pchunk,
    const int* __restrict__ iter_num,
    float* __restrict__ out) {
  int t = blockIdx.x * 128 + threadIdx.x;  // [0, 2*N)
  int i = t >> 1;                          // vertex
  int b = t & 1;                           // batch

  // weight ramp (double to match Python scalar math)
  int it = *iter_num;
  double itc = (double)(it - 50000);
  if (itc < 0.0) itc = 0.0;
  double prog = itc / 100000.0;
  if (prog > 1.0) prog = 1.0;
  float weight = (float)(1e-3 + (5e3 - 1e-3) * prog);
  float scale = weight * 0.5f;  // weight / B

  // independent loads hoisted: cloth_curr (pass-2 query) + cloth_next (plane)
  const float* cp = cloth_curr + ((size_t)b * N_ + i) * 3;
  float m2x = -2.0f * cp[0];
  float m2y = -2.0f * cp[1];
  float m2z = -2.0f * cp[2];
  const float* np2 = cloth_next + ((size_t)b * N_ + i) * 3;
  float nx = np2[0], ny = np2[1], nz = np2[2];

  // pass 1: argmin partition over chunk minima (8 float2 loads)
  float best = 3.4e38f;
  int bp = 0;
#pragma unroll
  for (int c = 0; c < NCHUNK_; ++c) {
    float2 v = pchunk[((size_t)(b * NCHUNK_ + c)) * N_ + i];
    bool mm = v.x < best;
    best = mm ? v.x : best;
    bp = mm ? __float_as_int(v.y) : bp;
  }

  // pass 2: exact fp32 rescan of winning partition
  const float4* fpp = fcurr + (size_t)b * F_ + (size_t)bp * TILE_;
  float sbest = 3.4e38f;
  int jwin = 0;
#pragma unroll 8
  for (int j = 0; j < TILE_; ++j) {
    float4 fc = fpp[j];
    float s = fmaf(m2x, fc.x, fmaf(m2y, fc.y, fmaf(m2z, fc.z, fc.w)));
    bool u = s < sbest;
    sbest = u ? s : sbest;
    jwin = u ? j : jwin;
  }
  int fidx = bp * TILE_ + jwin;

  float4 cent = fnext[2 * ((size_t)b * F_ + fidx) + 0];
  float4 nrm  = fnext[2 * ((size_t)b * F_ + fidx) + 1];
  float dist = (nx - cent.x) * nrm.x +
               (ny - cent.y) * nrm.y +
               (nz - cent.z) * nrm.z;
  float ip = fmaxf(1e-3f - dist, 0.0f);
  float acc = ip * ip * ip * scale;

  // combine the two batches (lanes 2k / 2k+1 hold b=0 / b=1 of vertex i)
  float pair = acc + __shfl_xor(acc, 1, 64);
  if (b == 0) out[1 + i] = pair;  // per_vert

  // block-level loss partial -> one atomic per block (2 waves)
  float r = acc;
#pragma unroll
  for (int off = 32; off > 0; off >>= 1) r += __shfl_down(r, off, 64);
  __shared__ float wsum[2];
  int lane = threadIdx.x & 63;
  int w = threadIdx.x >> 6;
  if (lane == 0) wsum[w] = r;
  __syncthreads();
  if (threadIdx.x == 0)
    atomicAdd(out, wsum[0] + wsum[1]);
}

// ---------------------------------------------------------------------------
extern "C" void kernel_launch(void* const* d_in, const int* in_sizes, int n_in,
                              void* d_out, int out_size, void* d_ws, size_t ws_size,
                              hipStream_t stream) {
  const float* cloth_curr = (const float*)d_in[0];
  const float* cloth_next = (const float*)d_in[1];
  const float* obs_curr   = (const float*)d_in[2];
  const float* obs_next   = (const float*)d_in[3];
  const int*   faces      = (const int*)d_in[4];
  const int*   iter_num   = (const int*)d_in[5];
  float* out = (float*)d_out;

  // workspace: fcurr 512K @0 | fnext 1M @512K | fpack 1M @1.5M | pchunk 2M @3.5M
  char* w = (char*)d_ws;
  float4* fcurr = (float4*)(w);
  float4* fnext = (float4*)(w + 524288);
  uint4*  fpack = (uint4*)(w + 1572864);
  float2* pchunk = (float2*)(w + 3670016);

  // wave-split: 512 blocks x 128 threads, block = 2 waves over 64 faces
  face_precomp<<<(B_ * F_) / 64, 128, 0, stream>>>(
      obs_curr, obs_next, faces, fcurr, fnext, fpack, out);

  knn_mfma32<<<1024, 256, 0, stream>>>(cloth_curr, fpack, pchunk);

  epilogue<<<(2 * N_ + 127) / 128, 128, 0, stream>>>(
      cloth_curr, cloth_next, fcurr, fnext, pchunk, iter_num, out);
}